// Round 4
// baseline (394.991 us; speedup 1.0000x reference)
//
#include <hip/hip_runtime.h>

// SNN forward: 2-neuron, 2-layer LIF over T timesteps, batch-parallel.
// Two batch elements per thread; time loop unrolled x4 with outputs batched
// in registers -> 12 back-to-back dwordx4 stores per waitcnt window (deep
// store MLP), plain stores (mirrors the 6.2 TB/s fill kernel's path).
//
// NOTE on numerics: spikes are Heaviside outputs -> any ulp difference near
// the threshold flips 0<->1 (absmax 1.0). We disable FP contraction and
// mirror the reference's fp32 expression ordering exactly.

typedef float floatv4 __attribute__((ext_vector_type(4)));  // native clang vec

__global__ __launch_bounds__(256) void snn_fwd_kernel(
    const float* __restrict__ x,      // [B,2]
    const float* __restrict__ fc1_w,  // [2,2] row-major
    const float* __restrict__ fc1_b,  // [2]
    const float* __restrict__ beta1,  // [1]
    const float* __restrict__ thr1,   // [1]
    const float* __restrict__ fc2_w,  // [2,2]
    const float* __restrict__ fc2_b,  // [2]
    const float* __restrict__ beta2,  // [1]
    const float* __restrict__ thr2,   // [1]
    float* __restrict__ out,          // [3, T, B, 2] concatenated
    int B2, int T)                    // B2 = B/2 (pairs), B = 2*B2
{
#pragma clang fp contract(off)
    int tid = blockIdx.x * blockDim.x + threadIdx.x;
    if (tid >= B2) return;

    // Two batch elements: (xv.x,xv.y) = elem a, (xv.z,xv.w) = elem b. 16B load.
    const floatv4 xv = ((const floatv4*)x)[tid];

    const float w00 = fc1_w[0], w01 = fc1_w[1], w10 = fc1_w[2], w11 = fc1_w[3];
    // cur1 = x @ fc1_w.T + fc1_b (constant over time; order: x0*w + x1*w, then +bias)
    const float ca0 = (xv.x * w00 + xv.y * w01) + fc1_b[0];
    const float ca1 = (xv.x * w10 + xv.y * w11) + fc1_b[1];
    const float cb0 = (xv.z * w00 + xv.w * w01) + fc1_b[0];
    const float cb1 = (xv.z * w10 + xv.w * w11) + fc1_b[1];

    const float b1 = fminf(fmaxf(beta1[0], 0.0f), 1.0f);
    const float b2 = fminf(fmaxf(beta2[0], 0.0f), 1.0f);
    const float t1 = thr1[0];
    const float t2 = thr2[0];

    const float v00 = fc2_w[0], v01 = fc2_w[1], v10 = fc2_w[2], v11 = fc2_w[3];
    const float fb0 = fc2_b[0], fb1 = fc2_b[1];

    // State for both elements.
    float m1a0 = 0.f, m1a1 = 0.f, m1b0 = 0.f, m1b1 = 0.f;
    float m2a0 = 0.f, m2a1 = 0.f, m2b0 = 0.f, m2b1 = 0.f;

    // One SNN step; writes the three output vectors for this timestep.
    auto step = [&](floatv4& o1, floatv4& o2, floatv4& o3) {
#pragma clang fp contract(off)
        const float r1a0 = ((m1a0 - t1) > 0.f) ? 1.f : 0.f;
        const float r1a1 = ((m1a1 - t1) > 0.f) ? 1.f : 0.f;
        const float r1b0 = ((m1b0 - t1) > 0.f) ? 1.f : 0.f;
        const float r1b1 = ((m1b1 - t1) > 0.f) ? 1.f : 0.f;
        m1a0 = (b1 * m1a0 + ca0) - r1a0 * t1;
        m1a1 = (b1 * m1a1 + ca1) - r1a1 * t1;
        m1b0 = (b1 * m1b0 + cb0) - r1b0 * t1;
        m1b1 = (b1 * m1b1 + cb1) - r1b1 * t1;
        const float s1a0 = ((m1a0 - t1) > 0.f) ? 1.f : 0.f;
        const float s1a1 = ((m1a1 - t1) > 0.f) ? 1.f : 0.f;
        const float s1b0 = ((m1b0 - t1) > 0.f) ? 1.f : 0.f;
        const float s1b1 = ((m1b1 - t1) > 0.f) ? 1.f : 0.f;
        const float c2a0 = (s1a0 * v00 + s1a1 * v01) + fb0;
        const float c2a1 = (s1a0 * v10 + s1a1 * v11) + fb1;
        const float c2b0 = (s1b0 * v00 + s1b1 * v01) + fb0;
        const float c2b1 = (s1b0 * v10 + s1b1 * v11) + fb1;
        const float r2a0 = ((m2a0 - t2) > 0.f) ? 1.f : 0.f;
        const float r2a1 = ((m2a1 - t2) > 0.f) ? 1.f : 0.f;
        const float r2b0 = ((m2b0 - t2) > 0.f) ? 1.f : 0.f;
        const float r2b1 = ((m2b1 - t2) > 0.f) ? 1.f : 0.f;
        m2a0 = (b2 * m2a0 + c2a0) - r2a0 * t2;
        m2a1 = (b2 * m2a1 + c2a1) - r2a1 * t2;
        m2b0 = (b2 * m2b0 + c2b0) - r2b0 * t2;
        m2b1 = (b2 * m2b1 + c2b1) - r2b1 * t2;
        const float s2a0 = ((m2a0 - t2) > 0.f) ? 1.f : 0.f;
        const float s2a1 = ((m2a1 - t2) > 0.f) ? 1.f : 0.f;
        const float s2b0 = ((m2b0 - t2) > 0.f) ? 1.f : 0.f;
        const float s2b1 = ((m2b1 - t2) > 0.f) ? 1.f : 0.f;
        o1.x = s1a0; o1.y = s1a1; o1.z = s1b0; o1.w = s1b1;
        o2.x = s2a0; o2.y = s2a1; o2.z = s2b0; o2.w = s2b1;
        o3.x = m2a0; o3.y = m2a1; o3.z = m2b0; o3.w = m2b1;
    };

    const size_t TB2 = (size_t)T * (size_t)B2;       // float4s per stream
    floatv4* __restrict__ spk1_out = (floatv4*)out;
    floatv4* __restrict__ spk2_out = (floatv4*)out + TB2;
    floatv4* __restrict__ mem2_out = (floatv4*)out + 2 * TB2;

    size_t off = (size_t)tid;
    int t = 0;
    // Main loop: 4 timesteps per iteration, outputs batched in registers,
    // then 12 stores issued back-to-back (deep vmcnt window).
    for (; t + 3 < T; t += 4, off += 4 * (size_t)B2) {
        floatv4 o1[4], o2[4], o3[4];
#pragma unroll
        for (int u = 0; u < 4; ++u)
            step(o1[u], o2[u], o3[u]);
#pragma unroll
        for (int u = 0; u < 4; ++u) {
            const size_t o = off + (size_t)u * (size_t)B2;
            spk1_out[o] = o1[u];
            spk2_out[o] = o2[u];
            mem2_out[o] = o3[u];
        }
    }
    // Tail (T not multiple of 4).
    for (; t < T; ++t, off += (size_t)B2) {
        floatv4 o1, o2, o3;
        step(o1, o2, o3);
        spk1_out[off] = o1;
        spk2_out[off] = o2;
        mem2_out[off] = o3;
    }
}

extern "C" void kernel_launch(void* const* d_in, const int* in_sizes, int n_in,
                              void* d_out, int out_size, void* d_ws, size_t ws_size,
                              hipStream_t stream) {
    const float* x      = (const float*)d_in[0];
    const float* fc1_w  = (const float*)d_in[1];
    const float* fc1_b  = (const float*)d_in[2];
    const float* beta1  = (const float*)d_in[3];
    const float* thr1   = (const float*)d_in[4];
    const float* fc2_w  = (const float*)d_in[5];
    const float* fc2_b  = (const float*)d_in[6];
    const float* beta2  = (const float*)d_in[7];
    const float* thr2   = (const float*)d_in[8];
    float* out = (float*)d_out;

    const int B  = in_sizes[0] / 2;           // x is [B,2]; B = 500000 (even)
    const int T  = out_size / (6 * B);        // out = 3 streams * T * B * 2
    const int B2 = B / 2;                     // pairs per thread

    const int block = 256;
    const int grid = (B2 + block - 1) / block;
    snn_fwd_kernel<<<grid, block, 0, stream>>>(x, fc1_w, fc1_b, beta1, thr1,
                                               fc2_w, fc2_b, beta2, thr2,
                                               out, B2, T);
}